// Round 7
// baseline (148.324 us; speedup 1.0000x reference)
//
#include <hip/hip_runtime.h>
#include <hip/hip_bf16.h>

#define LOG2E    1.4426950408889634f
#define TWOLOG2E 2.8853900817779268f

typedef short bf16x8 __attribute__((ext_vector_type(8)));
typedef float f32x4  __attribute__((ext_vector_type(4)));
typedef unsigned short u16x8 __attribute__((ext_vector_type(8)));

static __device__ __forceinline__ float bf16_to_f(unsigned short u) {
    union { unsigned int i; float f; } v; v.i = ((unsigned int)u) << 16; return v.f;
}
static __device__ __forceinline__ unsigned short f_to_bf16_rne(float x) {
    union { float f; unsigned int i; } v; v.f = x;
    unsigned int lsb = (v.i >> 16) & 1u;
    v.i += 0x7fffu + lsb;
    return (unsigned short)(v.i >> 16);
}

// ---------------------------------------------------------------------------
// cast_frag: f32 inputs -> split bf16 hi/lo in MFMA-fragment-linear layout.
// A entries: 144*24*64 = 221184 lane-records.  W: 96*24*64 = 147456.
// ---------------------------------------------------------------------------
__global__ __launch_bounds__(256) void cast_frag(
    const float* __restrict__ bert, const float* __restrict__ query,
    const float* __restrict__ Ww,
    unsigned short* __restrict__ Ahf, unsigned short* __restrict__ Alf,
    unsigned short* __restrict__ Whf, unsigned short* __restrict__ Wlf)
{
    const int i    = blockIdx.x * 256 + threadIdx.x;   // exact grid: 1440*256
    const int lane = i & 63;
    const float* src;
    float scale;
    unsigned short *dh, *dl;
    size_t di;
    if (i < 221184) {
        const int rest = i >> 6;
        const int kt = rest % 24, mt = rest / 24;
        const int m  = mt * 16 + (lane & 15);
        src = ((m < 2048) ? bert + (size_t)m * 768
                          : query + (size_t)(m - 2048) * 768)
              + kt * 32 + (lane >> 4) * 8;
        scale = 1.0f;
        dh = Ahf; dl = Alf; di = (size_t)i * 8;
    } else {
        const int j = i - 221184;
        const int rest = j >> 6;
        const int kt = rest % 24, nt2 = rest / 24;     // nt2 = sel*48 + nt
        const int sel = (nt2 >= 48) ? 1 : 0;
        const int n   = (nt2 - sel * 48) * 16 + (lane & 15);
        src = Ww + (size_t)n * 1536 + sel * 768 + kt * 32 + (lane >> 4) * 8;
        scale = TWOLOG2E;
        dh = Whf; dl = Wlf; di = (size_t)j * 8;
    }
    float4 x0 = *(const float4*)src;
    float4 x1 = *(const float4*)(src + 4);
    float xs[8] = {x0.x * scale, x0.y * scale, x0.z * scale, x0.w * scale,
                   x1.x * scale, x1.y * scale, x1.z * scale, x1.w * scale};
    u16x8 h, l;
    #pragma unroll
    for (int e = 0; e < 8; ++e) {
        unsigned short hh = f_to_bf16_rne(xs[e]);
        h[e] = hh;
        l[e] = f_to_bf16_rne(xs[e] - bf16_to_f(hh));
    }
    *(u16x8*)(dh + di) = h;
    *(u16x8*)(dl + di) = l;
}

// ---------------------------------------------------------------------------
// gemm_frag: split-bf16 3-pass MFMA, operands fragment-linear.
// 1 wave/block, wave tile 32x32, grid 72*24 = 1728.
// C[m][n] = sum_k A[m][k]*W'[n][k]  (+ TWOLOG2E*W_b[n] on query rows)
// ---------------------------------------------------------------------------
__global__ __launch_bounds__(64) void gemm_frag(
    const unsigned short* __restrict__ Ahf, const unsigned short* __restrict__ Alf,
    const unsigned short* __restrict__ Whf, const unsigned short* __restrict__ Wlf,
    const float* __restrict__ Wb, float* __restrict__ C)
{
    const int l    = threadIdx.x;
    const int w    = blockIdx.x;
    const int mt_w = w / 24;
    const int nt_w = w % 24;
    const int m0   = mt_w * 32;
    const int n0   = nt_w * 32;
    const bool isq = (m0 >= 2048);
    const int  fmt = mt_w * 2;
    const int  fnt = (isq ? 48 : 0) + nt_w * 2;
    const int  lr  = l & 15;
    const int  kg  = l >> 4;

    const unsigned short* pAh = Ahf + (size_t)fmt * 12288 + l * 8;
    const unsigned short* pAl = Alf + (size_t)fmt * 12288 + l * 8;
    const unsigned short* pBh = Whf + (size_t)fnt * 12288 + l * 8;
    const unsigned short* pBl = Wlf + (size_t)fnt * 12288 + l * 8;

    f32x4 acc[2][2];
    #pragma unroll
    for (int i = 0; i < 2; ++i)
        #pragma unroll
        for (int j = 0; j < 2; ++j) acc[i][j] = (f32x4){0.f, 0.f, 0.f, 0.f};

    #pragma unroll 4
    for (int kt = 0; kt < 24; ++kt) {
        bf16x8 ah[2], al[2], bh[2], bl[2];
        #pragma unroll
        for (int i = 0; i < 2; ++i) {
            ah[i] = *(const bf16x8*)(pAh + (size_t)i * 12288 + kt * 512);
            al[i] = *(const bf16x8*)(pAl + (size_t)i * 12288 + kt * 512);
            bh[i] = *(const bf16x8*)(pBh + (size_t)i * 12288 + kt * 512);
            bl[i] = *(const bf16x8*)(pBl + (size_t)i * 12288 + kt * 512);
        }
        #pragma unroll
        for (int i = 0; i < 2; ++i)
            #pragma unroll
            for (int j = 0; j < 2; ++j) {
                acc[i][j] = __builtin_amdgcn_mfma_f32_16x16x32_bf16(ah[i], bh[j], acc[i][j], 0, 0, 0);
                acc[i][j] = __builtin_amdgcn_mfma_f32_16x16x32_bf16(ah[i], bl[j], acc[i][j], 0, 0, 0);
                acc[i][j] = __builtin_amdgcn_mfma_f32_16x16x32_bf16(al[i], bh[j], acc[i][j], 0, 0, 0);
            }
    }

    #pragma unroll
    for (int j = 0; j < 2; ++j) {
        const int col  = n0 + j * 16 + lr;
        const float bias = isq ? Wb[col] * TWOLOG2E : 0.f;
        #pragma unroll
        for (int i = 0; i < 2; ++i)
            #pragma unroll
            for (int r = 0; r < 4; ++r) {
                const int row = m0 + i * 16 + kg * 4 + r;
                C[(size_t)row * 768 + col] = acc[i][j][r] + bias;
            }
    }
}

// ---------------------------------------------------------------------------
// attn_scores_part: k-split x4 partial of
//   X[b,q,l] = -2 * sum_k v_w[k] * rcp(1 + exp2(bp[l,k] + qp[q,k]))
// grid (32 ltiles, 4 qtiles, b*4+ks) = 2048 blocks -> 8 waves/SIMD.
// ---------------------------------------------------------------------------
__global__ __launch_bounds__(256) void attn_scores_part(
    const float* __restrict__ C, const float* __restrict__ v_w,
    float* __restrict__ Xp)
{
    const int t  = threadIdx.x;
    const int bz = blockIdx.z;        // b*4 + ks
    const int b  = bz >> 2;
    const int ks = bz & 3;
    const int q  = blockIdx.y * 16 + (t >> 4);
    const int lx = blockIdx.x * 16 + (t & 15);
    const int k0 = ks * 192;
    const float* pb = C + (size_t)(b * 512 + lx) * 768 + k0;
    const float* pq = C + (size_t)(2048 + b * 64 + q) * 768 + k0;
    const float* pv = v_w + k0;
    float acc = 0.f;
    #pragma unroll 4
    for (int k = 0; k < 192; k += 4) {
        float4 bv = *(const float4*)(pb + k);
        float4 qv = *(const float4*)(pq + k);
        float4 vv = *(const float4*)(pv + k);
        acc = fmaf(vv.x, __builtin_amdgcn_rcpf(1.0f + __builtin_amdgcn_exp2f(bv.x + qv.x)), acc);
        acc = fmaf(vv.y, __builtin_amdgcn_rcpf(1.0f + __builtin_amdgcn_exp2f(bv.y + qv.y)), acc);
        acc = fmaf(vv.z, __builtin_amdgcn_rcpf(1.0f + __builtin_amdgcn_exp2f(bv.z + qv.z)), acc);
        acc = fmaf(vv.w, __builtin_amdgcn_rcpf(1.0f + __builtin_amdgcn_exp2f(bv.w + qv.w)), acc);
    }
    Xp[(size_t)ks * 131072 + (size_t)(b * 64 + q) * 512 + lx] = acc;
}

// masked softmax over l (512) per (b,q) row; sums the 4 k-split partials
__global__ __launch_bounds__(512) void softmax_mask(
    const float* __restrict__ Xp, const int* __restrict__ mask,
    float* __restrict__ out)
{
    const int bq  = blockIdx.x;
    const int b   = bq >> 6;
    const int l   = threadIdx.x;
    const int wid = l >> 6;
    __shared__ float red[8];

    const size_t idx = (size_t)bq * 512 + l;
    float v = -2.f * (Xp[idx] + Xp[idx + 131072] + Xp[idx + 262144] + Xp[idx + 393216]);
    const bool mk = (mask[b * 512 + l] != 0);
    v = mk ? v : -1e25f;

    float m = v;
    #pragma unroll
    for (int o = 32; o; o >>= 1) m = fmaxf(m, __shfl_xor(m, o));
    if ((l & 63) == 0) red[wid] = m;
    __syncthreads();
    #pragma unroll
    for (int i = 0; i < 8; ++i) m = fmaxf(m, red[i]);

    float e = __builtin_amdgcn_exp2f((v - m) * LOG2E);
    float s = e;
    #pragma unroll
    for (int o = 32; o; o >>= 1) s += __shfl_xor(s, o);
    __syncthreads();
    if ((l & 63) == 0) red[wid] = s;
    __syncthreads();
    s = 0.f;
    #pragma unroll
    for (int i = 0; i < 8; ++i) s += red[i];

    out[idx] = e / s;
}

extern "C" void kernel_launch(void* const* d_in, const int* in_sizes, int n_in,
                              void* d_out, int out_size, void* d_ws, size_t ws_size,
                              hipStream_t stream)
{
    const float* bert  = (const float*)d_in[0];   // (4,512,768) f32
    const float* query = (const float*)d_in[1];   // (4,64,768)  f32
    const int*   mask  = (const int*)  d_in[2];   // (4,512)     int32 (bool)
    const float* W_w   = (const float*)d_in[3];   // (768,1536)  f32
    const float* W_b   = (const float*)d_in[4];   // (768,)      f32
    const float* v_w   = (const float*)d_in[5];   // (1,768)     f32
    const float* v_b   = (const float*)d_in[6];   // (1,) unused (softmax shift-invariant)
    (void)v_b;

    float* C  = (float*)d_ws;                      // [2304][768] f32
    float* Xp = C + (size_t)2304 * 768;            // [4][256][512] f32 partials
    unsigned short* Ahf = (unsigned short*)(Xp + (size_t)4 * 256 * 512);
    unsigned short* Alf = Ahf + (size_t)2304 * 768;
    unsigned short* Whf = Alf + (size_t)2304 * 768;
    unsigned short* Wlf = Whf + (size_t)1536 * 768;
    float* out = (float*)d_out;                    // (4,64,512) f32

    cast_frag<<<1440, 256, 0, stream>>>(bert, query, W_w, Ahf, Alf, Whf, Wlf);
    gemm_frag<<<1728, 64, 0, stream>>>(Ahf, Alf, Whf, Wlf, W_b, C);
    attn_scores_part<<<dim3(32, 4, 16), 256, 0, stream>>>(C, v_w, Xp);
    softmax_mask<<<dim3(256), 512, 0, stream>>>(Xp, mask, out);
}

// Round 8
// 130.354 us; speedup vs baseline: 1.1379x; 1.1379x over previous
//
#include <hip/hip_runtime.h>
#include <hip/hip_bf16.h>

#define LOG2E    1.4426950408889634f
#define TWOLOG2E 2.8853900817779268f

typedef short bf16x8 __attribute__((ext_vector_type(8)));
typedef float f32x4  __attribute__((ext_vector_type(4)));
typedef unsigned short u16x8 __attribute__((ext_vector_type(8)));

static __device__ __forceinline__ float bf16_to_f(unsigned short u) {
    union { unsigned int i; float f; } v; v.i = ((unsigned int)u) << 16; return v.f;
}
static __device__ __forceinline__ unsigned short f_to_bf16_rne(float x) {
    union { float f; unsigned int i; } v; v.f = x;
    unsigned int lsb = (v.i >> 16) & 1u;
    v.i += 0x7fffu + lsb;
    return (unsigned short)(v.i >> 16);
}

// ---------------------------------------------------------------------------
// cast_frag: f32 inputs -> split bf16 hi/lo in MFMA-fragment-linear layout.
// Layout identical to prior rounds (verified absmax 6e-5). A: 221184 lane-recs,
// W: 147456. W pre-scaled by 2*log2(e).
// ---------------------------------------------------------------------------
__global__ __launch_bounds__(256) void cast_frag(
    const float* __restrict__ bert, const float* __restrict__ query,
    const float* __restrict__ Ww,
    unsigned short* __restrict__ Ahf, unsigned short* __restrict__ Alf,
    unsigned short* __restrict__ Whf, unsigned short* __restrict__ Wlf)
{
    const int i    = blockIdx.x * 256 + threadIdx.x;   // exact grid: 1440*256
    const int lane = i & 63;
    const float* src;
    float scale;
    unsigned short *dh, *dl;
    size_t di;
    if (i < 221184) {
        const int rest = i >> 6;
        const int kt = rest % 24, mt = rest / 24;
        const int m  = mt * 16 + (lane & 15);
        src = ((m < 2048) ? bert + (size_t)m * 768
                          : query + (size_t)(m - 2048) * 768)
              + kt * 32 + (lane >> 4) * 8;
        scale = 1.0f;
        dh = Ahf; dl = Alf; di = (size_t)i * 8;
    } else {
        const int j = i - 221184;
        const int rest = j >> 6;
        const int kt = rest % 24, nt2 = rest / 24;     // nt2 = sel*48 + nt
        const int sel = (nt2 >= 48) ? 1 : 0;
        const int n   = (nt2 - sel * 48) * 16 + (lane & 15);
        src = Ww + (size_t)n * 1536 + sel * 768 + kt * 32 + (lane >> 4) * 8;
        scale = TWOLOG2E;
        dh = Whf; dl = Wlf; di = (size_t)j * 8;
    }
    float4 x0 = *(const float4*)src;
    float4 x1 = *(const float4*)(src + 4);
    float xs[8] = {x0.x * scale, x0.y * scale, x0.z * scale, x0.w * scale,
                   x1.x * scale, x1.y * scale, x1.z * scale, x1.w * scale};
    u16x8 h, l;
    #pragma unroll
    for (int e = 0; e < 8; ++e) {
        unsigned short hh = f_to_bf16_rne(xs[e]);
        h[e] = hh;
        l[e] = f_to_bf16_rne(xs[e] - bf16_to_f(hh));
    }
    *(u16x8*)(dh + di) = h;
    *(u16x8*)(dl + di) = l;
}

// ---------------------------------------------------------------------------
// gemm_frag: split-bf16 3-pass MFMA.
// bert tiles: OPERANDS SWAPPED -> D[n][m], stored dense as bpT[768][2048]
//   (A-frag and B-frag share the same lane->(idx,k) map, so swapping the
//    mfma args transposes the output for free; store pattern cost identical).
// query tiles: normal orientation -> qp[256][768] (+ scaled bias).
// 1 wave/block, wave tile 32x32, grid 72*24 = 1728.
// ---------------------------------------------------------------------------
__global__ __launch_bounds__(64) void gemm_frag(
    const unsigned short* __restrict__ Ahf, const unsigned short* __restrict__ Alf,
    const unsigned short* __restrict__ Whf, const unsigned short* __restrict__ Wlf,
    const float* __restrict__ Wb, float* __restrict__ bpT, float* __restrict__ qp)
{
    const int l    = threadIdx.x;
    const int w    = blockIdx.x;
    const int mt_w = w / 24;
    const int nt_w = w % 24;
    const int m0   = mt_w * 32;
    const int n0   = nt_w * 32;
    const bool isq = (m0 >= 2048);
    const int  fmt = mt_w * 2;
    const int  fnt = (isq ? 48 : 0) + nt_w * 2;
    const int  lr  = l & 15;
    const int  kg  = l >> 4;

    const unsigned short* pAh = Ahf + (size_t)fmt * 12288 + l * 8;
    const unsigned short* pAl = Alf + (size_t)fmt * 12288 + l * 8;
    const unsigned short* pBh = Whf + (size_t)fnt * 12288 + l * 8;
    const unsigned short* pBl = Wlf + (size_t)fnt * 12288 + l * 8;

    f32x4 acc[2][2];
    #pragma unroll
    for (int i = 0; i < 2; ++i)
        #pragma unroll
        for (int j = 0; j < 2; ++j) acc[i][j] = (f32x4){0.f, 0.f, 0.f, 0.f};

    if (!isq) {
        // ---- bert: acc[i][j] = W_frag[i] x bert_frag[j] -> D[n][m] ----
        #pragma unroll 4
        for (int kt = 0; kt < 24; ++kt) {
            bf16x8 ah[2], al[2], bh[2], bl[2];
            #pragma unroll
            for (int i = 0; i < 2; ++i) {
                ah[i] = *(const bf16x8*)(pAh + (size_t)i * 12288 + kt * 512);
                al[i] = *(const bf16x8*)(pAl + (size_t)i * 12288 + kt * 512);
                bh[i] = *(const bf16x8*)(pBh + (size_t)i * 12288 + kt * 512);
                bl[i] = *(const bf16x8*)(pBl + (size_t)i * 12288 + kt * 512);
            }
            #pragma unroll
            for (int i = 0; i < 2; ++i)
                #pragma unroll
                for (int j = 0; j < 2; ++j) {
                    acc[i][j] = __builtin_amdgcn_mfma_f32_16x16x32_bf16(bh[i], ah[j], acc[i][j], 0, 0, 0);
                    acc[i][j] = __builtin_amdgcn_mfma_f32_16x16x32_bf16(bh[i], al[j], acc[i][j], 0, 0, 0);
                    acc[i][j] = __builtin_amdgcn_mfma_f32_16x16x32_bf16(bl[i], ah[j], acc[i][j], 0, 0, 0);
                }
        }
        // store bpT[n][m], n = n0 + i*16 + kg*4 + r, m = m0 + j*16 + lr
        #pragma unroll
        for (int i = 0; i < 2; ++i)
            #pragma unroll
            for (int j = 0; j < 2; ++j)
                #pragma unroll
                for (int r = 0; r < 4; ++r) {
                    const int nrow = n0 + i * 16 + kg * 4 + r;
                    const int mcol = m0 + j * 16 + lr;
                    bpT[(size_t)nrow * 2048 + mcol] = acc[i][j][r];
                }
    } else {
        // ---- query: acc[i][j] = bert_frag[i] x W_frag[j] -> D[m][n] ----
        #pragma unroll 4
        for (int kt = 0; kt < 24; ++kt) {
            bf16x8 ah[2], al[2], bh[2], bl[2];
            #pragma unroll
            for (int i = 0; i < 2; ++i) {
                ah[i] = *(const bf16x8*)(pAh + (size_t)i * 12288 + kt * 512);
                al[i] = *(const bf16x8*)(pAl + (size_t)i * 12288 + kt * 512);
                bh[i] = *(const bf16x8*)(pBh + (size_t)i * 12288 + kt * 512);
                bl[i] = *(const bf16x8*)(pBl + (size_t)i * 12288 + kt * 512);
            }
            #pragma unroll
            for (int i = 0; i < 2; ++i)
                #pragma unroll
                for (int j = 0; j < 2; ++j) {
                    acc[i][j] = __builtin_amdgcn_mfma_f32_16x16x32_bf16(ah[i], bh[j], acc[i][j], 0, 0, 0);
                    acc[i][j] = __builtin_amdgcn_mfma_f32_16x16x32_bf16(ah[i], bl[j], acc[i][j], 0, 0, 0);
                    acc[i][j] = __builtin_amdgcn_mfma_f32_16x16x32_bf16(al[i], bh[j], acc[i][j], 0, 0, 0);
                }
        }
        #pragma unroll
        for (int j = 0; j < 2; ++j) {
            const int col  = n0 + j * 16 + lr;
            const float bias = Wb[col] * TWOLOG2E;
            #pragma unroll
            for (int i = 0; i < 2; ++i)
                #pragma unroll
                for (int r = 0; r < 4; ++r) {
                    const int row = m0 - 2048 + i * 16 + kg * 4 + r;
                    qp[(size_t)row * 768 + col] = acc[i][j][r] + bias;
                }
        }
    }
}

// ---------------------------------------------------------------------------
// attn_dense: Xp[ks][bq][l] = sum_{k in chunk} v_w[k] * rcp(1+exp2(bpT[k][m]+qp[bq][k]))
// bpT loads are lane-dense (1KB/wave-load); qp/v_w are block-uniform (s_load).
// block 128 thr (2 waves) handles one bq, 4 l per thread; grid (256 bq, 8 ks)
// = 2048 blocks = 4096 waves = 4 waves/SIMD.
// ---------------------------------------------------------------------------
__global__ __launch_bounds__(128) void attn_dense(
    const float* __restrict__ bpT, const float* __restrict__ qp,
    const float* __restrict__ v_w, float* __restrict__ Xp)
{
    const int t  = threadIdx.x;        // 0..127 -> l = 4t
    const int bq = blockIdx.x;         // 0..255
    const int ks = blockIdx.y;         // 0..7
    const int b  = bq >> 6;
    const int k0 = ks * 96;
    const float* bT = bpT + (size_t)b * 512 + t * 4;
    const float* pq = qp + (size_t)bq * 768;
    f32x4 acc = {0.f, 0.f, 0.f, 0.f};
    #pragma unroll 4
    for (int k = k0; k < k0 + 96; ++k) {
        float4 bv = *(const float4*)(bT + (size_t)k * 2048);
        const float qk = pq[k];
        const float vk = v_w[k];
        acc[0] = fmaf(vk, __builtin_amdgcn_rcpf(1.0f + __builtin_amdgcn_exp2f(bv.x + qk)), acc[0]);
        acc[1] = fmaf(vk, __builtin_amdgcn_rcpf(1.0f + __builtin_amdgcn_exp2f(bv.y + qk)), acc[1]);
        acc[2] = fmaf(vk, __builtin_amdgcn_rcpf(1.0f + __builtin_amdgcn_exp2f(bv.z + qk)), acc[2]);
        acc[3] = fmaf(vk, __builtin_amdgcn_rcpf(1.0f + __builtin_amdgcn_exp2f(bv.w + qk)), acc[3]);
    }
    *(f32x4*)(Xp + (size_t)ks * 131072 + (size_t)bq * 512 + t * 4) = acc;
}

// masked softmax over l (512) per (b,q) row; sums the 8 k-split partials
__global__ __launch_bounds__(512) void softmax_mask(
    const float* __restrict__ Xp, const int* __restrict__ mask,
    float* __restrict__ out)
{
    const int bq  = blockIdx.x;
    const int b   = bq >> 6;
    const int l   = threadIdx.x;
    const int wid = l >> 6;
    __shared__ float red[8];

    const size_t idx = (size_t)bq * 512 + l;
    float v = 0.f;
    #pragma unroll
    for (int p = 0; p < 8; ++p) v += Xp[idx + (size_t)p * 131072];
    v *= -2.f;
    const bool mk = (mask[b * 512 + l] != 0);
    v = mk ? v : -1e25f;

    float m = v;
    #pragma unroll
    for (int o = 32; o; o >>= 1) m = fmaxf(m, __shfl_xor(m, o));
    if ((l & 63) == 0) red[wid] = m;
    __syncthreads();
    #pragma unroll
    for (int i = 0; i < 8; ++i) m = fmaxf(m, red[i]);

    float e = __builtin_amdgcn_exp2f((v - m) * LOG2E);
    float s = e;
    #pragma unroll
    for (int o = 32; o; o >>= 1) s += __shfl_xor(s, o);
    __syncthreads();
    if ((l & 63) == 0) red[wid] = s;
    __syncthreads();
    s = 0.f;
    #pragma unroll
    for (int i = 0; i < 8; ++i) s += red[i];

    out[idx] = e / s;
}

extern "C" void kernel_launch(void* const* d_in, const int* in_sizes, int n_in,
                              void* d_out, int out_size, void* d_ws, size_t ws_size,
                              hipStream_t stream)
{
    const float* bert  = (const float*)d_in[0];   // (4,512,768) f32
    const float* query = (const float*)d_in[1];   // (4,64,768)  f32
    const int*   mask  = (const int*)  d_in[2];   // (4,512)     int32 (bool)
    const float* W_w   = (const float*)d_in[3];   // (768,1536)  f32
    const float* W_b   = (const float*)d_in[4];   // (768,)      f32
    const float* v_w   = (const float*)d_in[5];   // (1,768)     f32
    const float* v_b   = (const float*)d_in[6];   // (1,) unused (softmax shift-invariant)
    (void)v_b;

    float* bpT = (float*)d_ws;                     // [768][2048] f32 (k-major!)
    float* qp  = bpT + (size_t)768 * 2048;         // [256][768]  f32
    float* Xp  = qp  + (size_t)256 * 768;          // [8][256][512] f32 partials
    unsigned short* Ahf = (unsigned short*)(Xp + (size_t)8 * 256 * 512);
    unsigned short* Alf = Ahf + (size_t)2304 * 768;
    unsigned short* Whf = Alf + (size_t)2304 * 768;
    unsigned short* Wlf = Whf + (size_t)1536 * 768;
    float* out = (float*)d_out;                    // (4,64,512) f32

    cast_frag<<<1440, 256, 0, stream>>>(bert, query, W_w, Ahf, Alf, Whf, Wlf);
    gemm_frag<<<1728, 64, 0, stream>>>(Ahf, Alf, Whf, Wlf, W_b, bpT, qp);
    attn_dense<<<dim3(256, 8), 128, 0, stream>>>(bpT, qp, v_w, Xp);
    softmax_mask<<<dim3(256), 512, 0, stream>>>(Xp, mask, out);
}

// Round 9
// 120.512 us; speedup vs baseline: 1.2308x; 1.0817x over previous
//
#include <hip/hip_runtime.h>
#include <hip/hip_bf16.h>

#define LOG2E    1.4426950408889634f
#define TWOLOG2E 2.8853900817779268f

typedef short bf16x8 __attribute__((ext_vector_type(8)));
typedef float f32x4  __attribute__((ext_vector_type(4)));
typedef unsigned short u16x8 __attribute__((ext_vector_type(8)));

static __device__ __forceinline__ float bf16_to_f(unsigned short u) {
    union { unsigned int i; float f; } v; v.i = ((unsigned int)u) << 16; return v.f;
}
static __device__ __forceinline__ unsigned short f_to_bf16_rne(float x) {
    union { float f; unsigned int i; } v; v.f = x;
    unsigned int lsb = (v.i >> 16) & 1u;
    v.i += 0x7fffu + lsb;
    return (unsigned short)(v.i >> 16);
}

// ---------------------------------------------------------------------------
// cast_frag: f32 inputs -> split bf16 hi/lo in MFMA-fragment-linear layout.
// (unchanged; verified absmax 6e-5). W pre-scaled by 2*log2(e).
// ---------------------------------------------------------------------------
__global__ __launch_bounds__(256) void cast_frag(
    const float* __restrict__ bert, const float* __restrict__ query,
    const float* __restrict__ Ww,
    unsigned short* __restrict__ Ahf, unsigned short* __restrict__ Alf,
    unsigned short* __restrict__ Whf, unsigned short* __restrict__ Wlf)
{
    const int i    = blockIdx.x * 256 + threadIdx.x;   // exact grid: 1440*256
    const int lane = i & 63;
    const float* src;
    float scale;
    unsigned short *dh, *dl;
    size_t di;
    if (i < 221184) {
        const int rest = i >> 6;
        const int kt = rest % 24, mt = rest / 24;
        const int m  = mt * 16 + (lane & 15);
        src = ((m < 2048) ? bert + (size_t)m * 768
                          : query + (size_t)(m - 2048) * 768)
              + kt * 32 + (lane >> 4) * 8;
        scale = 1.0f;
        dh = Ahf; dl = Alf; di = (size_t)i * 8;
    } else {
        const int j = i - 221184;
        const int rest = j >> 6;
        const int kt = rest % 24, nt2 = rest / 24;     // nt2 = sel*48 + nt
        const int sel = (nt2 >= 48) ? 1 : 0;
        const int n   = (nt2 - sel * 48) * 16 + (lane & 15);
        src = Ww + (size_t)n * 1536 + sel * 768 + kt * 32 + (lane >> 4) * 8;
        scale = TWOLOG2E;
        dh = Whf; dl = Wlf; di = (size_t)j * 8;
    }
    float4 x0 = *(const float4*)src;
    float4 x1 = *(const float4*)(src + 4);
    float xs[8] = {x0.x * scale, x0.y * scale, x0.z * scale, x0.w * scale,
                   x1.x * scale, x1.y * scale, x1.z * scale, x1.w * scale};
    u16x8 h, l;
    #pragma unroll
    for (int e = 0; e < 8; ++e) {
        unsigned short hh = f_to_bf16_rne(xs[e]);
        h[e] = hh;
        l[e] = f_to_bf16_rne(xs[e] - bf16_to_f(hh));
    }
    *(u16x8*)(dh + di) = h;
    *(u16x8*)(dl + di) = l;
}

// ---------------------------------------------------------------------------
// gemm_frag: split-bf16 3-pass MFMA, wave tile 32(m) x 16(n).
// grid = 72 mt * 48 nt = 3456 one-wave blocks (3.4 waves/SIMD, was 1.7).
// bert tiles: operands swapped -> D[n][m], stored dense into bpT[768][2048].
// query tiles: normal -> qp[256][768] (+ scaled bias).
// ---------------------------------------------------------------------------
__global__ __launch_bounds__(64) void gemm_frag(
    const unsigned short* __restrict__ Ahf, const unsigned short* __restrict__ Alf,
    const unsigned short* __restrict__ Whf, const unsigned short* __restrict__ Wlf,
    const float* __restrict__ Wb, float* __restrict__ bpT, float* __restrict__ qp)
{
    const int l    = threadIdx.x;
    const int w    = blockIdx.x;
    const int mt_w = w / 48;                 // 0..71
    const int nt_w = w % 48;                 // 0..47 (16-col units)
    const int m0   = mt_w * 32;
    const int n16  = nt_w * 16;
    const bool isq = (m0 >= 2048);
    const int  fmt = mt_w * 2;               // A frag tile (16-row) index
    const int  fnt = (isq ? 48 : 0) + nt_w;  // W frag tile index
    const int  lr  = l & 15;
    const int  kg  = l >> 4;

    const unsigned short* pAh = Ahf + (size_t)fmt * 12288 + l * 8;
    const unsigned short* pAl = Alf + (size_t)fmt * 12288 + l * 8;
    const unsigned short* pBh = Whf + (size_t)fnt * 12288 + l * 8;
    const unsigned short* pBl = Wlf + (size_t)fnt * 12288 + l * 8;

    f32x4 acc[2];
    acc[0] = (f32x4){0.f, 0.f, 0.f, 0.f};
    acc[1] = (f32x4){0.f, 0.f, 0.f, 0.f};

    if (!isq) {
        #pragma unroll 4
        for (int kt = 0; kt < 24; ++kt) {
            bf16x8 ah[2], al[2], bh, bl;
            #pragma unroll
            for (int i = 0; i < 2; ++i) {
                ah[i] = *(const bf16x8*)(pAh + (size_t)i * 12288 + kt * 512);
                al[i] = *(const bf16x8*)(pAl + (size_t)i * 12288 + kt * 512);
            }
            bh = *(const bf16x8*)(pBh + kt * 512);
            bl = *(const bf16x8*)(pBl + kt * 512);
            #pragma unroll
            for (int j = 0; j < 2; ++j) {
                acc[j] = __builtin_amdgcn_mfma_f32_16x16x32_bf16(bh, ah[j], acc[j], 0, 0, 0);
                acc[j] = __builtin_amdgcn_mfma_f32_16x16x32_bf16(bh, al[j], acc[j], 0, 0, 0);
                acc[j] = __builtin_amdgcn_mfma_f32_16x16x32_bf16(bl, ah[j], acc[j], 0, 0, 0);
            }
        }
        // D[n][m]: n = n16 + kg*4 + r, m = m0 + j*16 + lr
        #pragma unroll
        for (int j = 0; j < 2; ++j)
            #pragma unroll
            for (int r = 0; r < 4; ++r) {
                const int nrow = n16 + kg * 4 + r;
                const int mcol = m0 + j * 16 + lr;
                bpT[(size_t)nrow * 2048 + mcol] = acc[j][r];
            }
    } else {
        #pragma unroll 4
        for (int kt = 0; kt < 24; ++kt) {
            bf16x8 ah[2], al[2], bh, bl;
            #pragma unroll
            for (int i = 0; i < 2; ++i) {
                ah[i] = *(const bf16x8*)(pAh + (size_t)i * 12288 + kt * 512);
                al[i] = *(const bf16x8*)(pAl + (size_t)i * 12288 + kt * 512);
            }
            bh = *(const bf16x8*)(pBh + kt * 512);
            bl = *(const bf16x8*)(pBl + kt * 512);
            #pragma unroll
            for (int i = 0; i < 2; ++i) {
                acc[i] = __builtin_amdgcn_mfma_f32_16x16x32_bf16(ah[i], bh, acc[i], 0, 0, 0);
                acc[i] = __builtin_amdgcn_mfma_f32_16x16x32_bf16(ah[i], bl, acc[i], 0, 0, 0);
                acc[i] = __builtin_amdgcn_mfma_f32_16x16x32_bf16(al[i], bh, acc[i], 0, 0, 0);
            }
        }
        const int col  = n16 + lr;
        const float bias = Wb[col] * TWOLOG2E;
        #pragma unroll
        for (int i = 0; i < 2; ++i)
            #pragma unroll
            for (int r = 0; r < 4; ++r) {
                const int row = m0 - 2048 + i * 16 + kg * 4 + r;
                qp[(size_t)row * 768 + col] = acc[i][r] + bias;
            }
    }
}

// ---------------------------------------------------------------------------
// attn_dense: Xp[ks][bq][l] = sum_{k in 48-chunk} v_w[k]*rcp(1+exp2(bpT[k][m]+qp[bq][k]))
// grid (256 bq, 16 ks) = 4096 blocks x 2 waves = 8 waves/SIMD; unroll 8
// -> 32 independent trans chains per wave to cover exp2/rcp latency.
// ---------------------------------------------------------------------------
__global__ __launch_bounds__(128) void attn_dense(
    const float* __restrict__ bpT, const float* __restrict__ qp,
    const float* __restrict__ v_w, float* __restrict__ Xp)
{
    const int t  = threadIdx.x;        // 0..127 -> l = 4t
    const int bq = blockIdx.x;         // 0..255
    const int ks = blockIdx.y;         // 0..15
    const int b  = bq >> 6;
    const int k0 = ks * 48;
    const float* bT = bpT + (size_t)b * 512 + t * 4;
    const float* pq = qp + (size_t)bq * 768;
    f32x4 acc = {0.f, 0.f, 0.f, 0.f};
    #pragma unroll 8
    for (int k = k0; k < k0 + 48; ++k) {
        float4 bv = *(const float4*)(bT + (size_t)k * 2048);
        const float qk = pq[k];
        const float vk = v_w[k];
        acc[0] = fmaf(vk, __builtin_amdgcn_rcpf(1.0f + __builtin_amdgcn_exp2f(bv.x + qk)), acc[0]);
        acc[1] = fmaf(vk, __builtin_amdgcn_rcpf(1.0f + __builtin_amdgcn_exp2f(bv.y + qk)), acc[1]);
        acc[2] = fmaf(vk, __builtin_amdgcn_rcpf(1.0f + __builtin_amdgcn_exp2f(bv.z + qk)), acc[2]);
        acc[3] = fmaf(vk, __builtin_amdgcn_rcpf(1.0f + __builtin_amdgcn_exp2f(bv.w + qk)), acc[3]);
    }
    *(f32x4*)(Xp + (size_t)ks * 131072 + (size_t)bq * 512 + t * 4) = acc;
}

// masked softmax over l (512) per (b,q) row; sums the 16 k-split partials
__global__ __launch_bounds__(512) void softmax_mask(
    const float* __restrict__ Xp, const int* __restrict__ mask,
    float* __restrict__ out)
{
    const int bq  = blockIdx.x;
    const int b   = bq >> 6;
    const int l   = threadIdx.x;
    const int wid = l >> 6;
    __shared__ float red[8];

    const size_t idx = (size_t)bq * 512 + l;
    float v = 0.f;
    #pragma unroll
    for (int p = 0; p < 16; ++p) v += Xp[idx + (size_t)p * 131072];
    v *= -2.f;
    const bool mk = (mask[b * 512 + l] != 0);
    v = mk ? v : -1e25f;

    float m = v;
    #pragma unroll
    for (int o = 32; o; o >>= 1) m = fmaxf(m, __shfl_xor(m, o));
    if ((l & 63) == 0) red[wid] = m;
    __syncthreads();
    #pragma unroll
    for (int i = 0; i < 8; ++i) m = fmaxf(m, red[i]);

    float e = __builtin_amdgcn_exp2f((v - m) * LOG2E);
    float s = e;
    #pragma unroll
    for (int o = 32; o; o >>= 1) s += __shfl_xor(s, o);
    __syncthreads();
    if ((l & 63) == 0) red[wid] = s;
    __syncthreads();
    s = 0.f;
    #pragma unroll
    for (int i = 0; i < 8; ++i) s += red[i];

    out[idx] = e / s;
}

extern "C" void kernel_launch(void* const* d_in, const int* in_sizes, int n_in,
                              void* d_out, int out_size, void* d_ws, size_t ws_size,
                              hipStream_t stream)
{
    const float* bert  = (const float*)d_in[0];   // (4,512,768) f32
    const float* query = (const float*)d_in[1];   // (4,64,768)  f32
    const int*   mask  = (const int*)  d_in[2];   // (4,512)     int32 (bool)
    const float* W_w   = (const float*)d_in[3];   // (768,1536)  f32
    const float* W_b   = (const float*)d_in[4];   // (768,)      f32
    const float* v_w   = (const float*)d_in[5];   // (1,768)     f32
    const float* v_b   = (const float*)d_in[6];   // (1,) unused (softmax shift-invariant)
    (void)v_b;

    float* bpT = (float*)d_ws;                     // [768][2048] f32 (k-major)
    float* qp  = bpT + (size_t)768 * 2048;         // [256][768]  f32
    float* Xp  = qp  + (size_t)256 * 768;          // [16][256][512] f32 partials
    unsigned short* Ahf = (unsigned short*)(Xp + (size_t)16 * 256 * 512);
    unsigned short* Alf = Ahf + (size_t)2304 * 768;
    unsigned short* Whf = Alf + (size_t)2304 * 768;
    unsigned short* Wlf = Whf + (size_t)1536 * 768;
    float* out = (float*)d_out;                    // (4,64,512) f32

    cast_frag<<<1440, 256, 0, stream>>>(bert, query, W_w, Ahf, Alf, Whf, Wlf);
    gemm_frag<<<3456, 64, 0, stream>>>(Ahf, Alf, Whf, Wlf, W_b, bpT, qp);
    attn_dense<<<dim3(256, 16), 128, 0, stream>>>(bpT, qp, v_w, Xp);
    softmax_mask<<<dim3(256), 512, 0, stream>>>(Xp, mask, out);
}

// Round 11
// 118.711 us; speedup vs baseline: 1.2495x; 1.0152x over previous
//
#include <hip/hip_runtime.h>
#include <hip/hip_bf16.h>

#define LOG2E    1.4426950408889634f
#define TWOLOG2E 2.8853900817779268f

typedef short bf16x8 __attribute__((ext_vector_type(8)));
typedef float f32x4  __attribute__((ext_vector_type(4)));
typedef unsigned short u16x8 __attribute__((ext_vector_type(8)));

static __device__ __forceinline__ float bf16_to_f(unsigned short u) {
    union { unsigned int i; float f; } v; v.i = ((unsigned int)u) << 16; return v.f;
}
static __device__ __forceinline__ unsigned short f_to_bf16_rne(float x) {
    union { float f; unsigned int i; } v; v.f = x;
    unsigned int lsb = (v.i >> 16) & 1u;
    v.i += 0x7fffu + lsb;
    return (unsigned short)(v.i >> 16);
}

// ---------------------------------------------------------------------------
// cast_frag: f32 inputs -> split bf16 hi/lo in MFMA-fragment-linear layout.
// (unchanged; verified absmax 6e-5). W pre-scaled by 2*log2(e).
// frag-record: 16-row tile f, k-tile kt, lane l -> shorts at f*12288+kt*512+l*8
// ---------------------------------------------------------------------------
__global__ __launch_bounds__(256) void cast_frag(
    const float* __restrict__ bert, const float* __restrict__ query,
    const float* __restrict__ Ww,
    unsigned short* __restrict__ Ahf, unsigned short* __restrict__ Alf,
    unsigned short* __restrict__ Whf, unsigned short* __restrict__ Wlf)
{
    const int i    = blockIdx.x * 256 + threadIdx.x;   // exact grid: 1440*256
    const int lane = i & 63;
    const float* src;
    float scale;
    unsigned short *dh, *dl;
    size_t di;
    if (i < 221184) {
        const int rest = i >> 6;
        const int kt = rest % 24, mt = rest / 24;
        const int m  = mt * 16 + (lane & 15);
        src = ((m < 2048) ? bert + (size_t)m * 768
                          : query + (size_t)(m - 2048) * 768)
              + kt * 32 + (lane >> 4) * 8;
        scale = 1.0f;
        dh = Ahf; dl = Alf; di = (size_t)i * 8;
    } else {
        const int j = i - 221184;
        const int rest = j >> 6;
        const int kt = rest % 24, nt2 = rest / 24;     // nt2 = sel*48 + nt
        const int sel = (nt2 >= 48) ? 1 : 0;
        const int n   = (nt2 - sel * 48) * 16 + (lane & 15);
        src = Ww + (size_t)n * 1536 + sel * 768 + kt * 32 + (lane >> 4) * 8;
        scale = TWOLOG2E;
        dh = Whf; dl = Wlf; di = (size_t)j * 8;
    }
    float4 x0 = *(const float4*)src;
    float4 x1 = *(const float4*)(src + 4);
    float xs[8] = {x0.x * scale, x0.y * scale, x0.z * scale, x0.w * scale,
                   x1.x * scale, x1.y * scale, x1.z * scale, x1.w * scale};
    u16x8 h, l;
    #pragma unroll
    for (int e = 0; e < 8; ++e) {
        unsigned short hh = f_to_bf16_rne(xs[e]);
        h[e] = hh;
        l[e] = f_to_bf16_rne(xs[e] - bf16_to_f(hh));
    }
    *(u16x8*)(dh + di) = h;
    *(u16x8*)(dl + di) = l;
}

// ---------------------------------------------------------------------------
// gemm_lds: split-bf16 3-pass MFMA with LDS-staged operands.
// Block = 256 thr (4 waves, 2x2), tile 64m x 64n; wave tile 32x32.
// Per kt: 16 x 1KB records staged via global_load_lds(16B); each wave then
// 8 ds_read_b128 + 12 MFMA. Grid = 36 mt2 * 12 nt2 = 432.
// bert blocks (mt2<32): swapped operands -> bpT[768][2048] (k-major).
// query blocks: normal -> qp[256][768] + scaled bias.
// ---------------------------------------------------------------------------
__global__ __launch_bounds__(256) void gemm_lds(
    const unsigned short* __restrict__ Ahf, const unsigned short* __restrict__ Alf,
    const unsigned short* __restrict__ Whf, const unsigned short* __restrict__ Wlf,
    const float* __restrict__ Wb, float* __restrict__ bpT, float* __restrict__ qp)
{
    __shared__ short lds[8192];              // 16 records x 1KB = 16 KB

    const int t    = threadIdx.x;
    const int w    = t >> 6;                 // wave 0..3
    const int lane = t & 63;
    const int wi   = w >> 1;                 // m half
    const int wj   = w & 1;                  // n half
    const int lr   = lane & 15;
    const int kg   = lane >> 4;

    const int blk  = blockIdx.x;
    const int mt2  = blk / 12;               // 0..35 (64-row tiles)
    const int nt2  = blk % 12;               // 0..11 (64-col tiles)
    const bool isq = (mt2 >= 32);
    const int fmtA = mt2 * 4;                // first 16-row frag tile of A
    const int fntB = (isq ? 48 : 0) + nt2 * 4;

    // staging source base (this thread stages records 4w..4w+3)
    const unsigned short* gsrc[4];
    #pragma unroll
    for (int c = 0; c < 4; ++c) {
        const int r = w * 4 + c;
        if (r < 8) {
            const int f = r >> 1;
            gsrc[c] = ((r & 1) ? Alf : Ahf) + (size_t)(fmtA + f) * 12288 + lane * 8;
        } else {
            const int f = (r - 8) >> 1;
            gsrc[c] = ((r & 1) ? Wlf : Whf) + (size_t)(fntB + f) * 12288 + lane * 8;
        }
    }

    f32x4 acc[2][2];
    #pragma unroll
    for (int i = 0; i < 2; ++i)
        #pragma unroll
        for (int j = 0; j < 2; ++j) acc[i][j] = (f32x4){0.f, 0.f, 0.f, 0.f};

    for (int kt = 0; kt < 24; ++kt) {
        // stage 16 records for this kt
        #pragma unroll
        for (int c = 0; c < 4; ++c) {
            const int r = w * 4 + c;
            __builtin_amdgcn_global_load_lds(
                (const __attribute__((address_space(1))) unsigned int*)(gsrc[c] + kt * 512),
                (__attribute__((address_space(3))) unsigned int*)&lds[r * 512],
                16, 0, 0);
        }
        __syncthreads();   // drains vmcnt + barrier

        bf16x8 ah[2], al[2], bh[2], bl[2];
        #pragma unroll
        for (int ii = 0; ii < 2; ++ii) {
            const int a = 2 * wi + ii;
            ah[ii] = *(const bf16x8*)&lds[(a * 2 + 0) * 512 + lane * 8];
            al[ii] = *(const bf16x8*)&lds[(a * 2 + 1) * 512 + lane * 8];
        }
        #pragma unroll
        for (int jj = 0; jj < 2; ++jj) {
            const int b = 2 * wj + jj;
            bh[jj] = *(const bf16x8*)&lds[4096 + (b * 2 + 0) * 512 + lane * 8];
            bl[jj] = *(const bf16x8*)&lds[4096 + (b * 2 + 1) * 512 + lane * 8];
        }

        if (!isq) {
            #pragma unroll
            for (int ii = 0; ii < 2; ++ii)
                #pragma unroll
                for (int jj = 0; jj < 2; ++jj) {
                    acc[ii][jj] = __builtin_amdgcn_mfma_f32_16x16x32_bf16(bh[jj], ah[ii], acc[ii][jj], 0, 0, 0);
                    acc[ii][jj] = __builtin_amdgcn_mfma_f32_16x16x32_bf16(bh[jj], al[ii], acc[ii][jj], 0, 0, 0);
                    acc[ii][jj] = __builtin_amdgcn_mfma_f32_16x16x32_bf16(bl[jj], ah[ii], acc[ii][jj], 0, 0, 0);
                }
        } else {
            #pragma unroll
            for (int ii = 0; ii < 2; ++ii)
                #pragma unroll
                for (int jj = 0; jj < 2; ++jj) {
                    acc[ii][jj] = __builtin_amdgcn_mfma_f32_16x16x32_bf16(ah[ii], bh[jj], acc[ii][jj], 0, 0, 0);
                    acc[ii][jj] = __builtin_amdgcn_mfma_f32_16x16x32_bf16(ah[ii], bl[jj], acc[ii][jj], 0, 0, 0);
                    acc[ii][jj] = __builtin_amdgcn_mfma_f32_16x16x32_bf16(al[ii], bh[jj], acc[ii][jj], 0, 0, 0);
                }
        }
        __syncthreads();   // protect LDS before next stage
    }

    const int m0 = mt2 * 64 + wi * 32;
    const int n0 = nt2 * 64 + wj * 32;
    if (!isq) {
        // D[n][m]: n = n0 + jj*16 + kg*4 + r ; m = m0 + ii*16 + lr
        #pragma unroll
        for (int ii = 0; ii < 2; ++ii)
            #pragma unroll
            for (int jj = 0; jj < 2; ++jj)
                #pragma unroll
                for (int r = 0; r < 4; ++r) {
                    const int nrow = n0 + jj * 16 + kg * 4 + r;
                    const int mcol = m0 + ii * 16 + lr;
                    bpT[(size_t)nrow * 2048 + mcol] = acc[ii][jj][r];
                }
    } else {
        #pragma unroll
        for (int jj = 0; jj < 2; ++jj) {
            const int col  = n0 + jj * 16 + lr;
            const float bias = Wb[col] * TWOLOG2E;
            #pragma unroll
            for (int ii = 0; ii < 2; ++ii)
                #pragma unroll
                for (int r = 0; r < 4; ++r) {
                    const int row = m0 - 2048 + ii * 16 + kg * 4 + r;
                    qp[(size_t)row * 768 + col] = acc[ii][jj][r] + bias;
                }
        }
    }
}

// ---------------------------------------------------------------------------
// attn_dense4: 4 q's per block share each bpT read (L2 traffic /4).
// Xp[ks][b*64+q][l] = sum_{k in 48-chunk} v_w[k]*rcp(1+exp2(bpT[k][l_b]+qp[bq][k]))
// grid (64 bq-tiles, 16 ks) = 1024 blocks x 2 waves; 16 independent sigma
// chains per k per thread for trans-pipe ILP.
// ---------------------------------------------------------------------------
__global__ __launch_bounds__(128) void attn_dense4(
    const float* __restrict__ bpT, const float* __restrict__ qp,
    const float* __restrict__ v_w, float* __restrict__ Xp)
{
    const int t   = threadIdx.x;       // 0..127 -> l = 4t
    const int bqt = blockIdx.x;        // 0..63
    const int ks  = blockIdx.y;        // 0..15
    const int b   = bqt >> 4;
    const int q0  = (bqt & 15) * 4;
    const int k0  = ks * 48;
    const float* bT = bpT + (size_t)b * 512 + t * 4;
    const float* pq = qp + (size_t)(b * 64 + q0) * 768;
    f32x4 acc[4];
    #pragma unroll
    for (int qi = 0; qi < 4; ++qi) acc[qi] = (f32x4){0.f, 0.f, 0.f, 0.f};

    #pragma unroll 4
    for (int k = k0; k < k0 + 48; ++k) {
        float4 bv = *(const float4*)(bT + (size_t)k * 2048);
        const float vk = v_w[k];
        float qk[4] = {pq[k], pq[768 + k], pq[1536 + k], pq[2304 + k]};
        #pragma unroll
        for (int qi = 0; qi < 4; ++qi) {
            acc[qi][0] = fmaf(vk, __builtin_amdgcn_rcpf(1.0f + __builtin_amdgcn_exp2f(bv.x + qk[qi])), acc[qi][0]);
            acc[qi][1] = fmaf(vk, __builtin_amdgcn_rcpf(1.0f + __builtin_amdgcn_exp2f(bv.y + qk[qi])), acc[qi][1]);
            acc[qi][2] = fmaf(vk, __builtin_amdgcn_rcpf(1.0f + __builtin_amdgcn_exp2f(bv.z + qk[qi])), acc[qi][2]);
            acc[qi][3] = fmaf(vk, __builtin_amdgcn_rcpf(1.0f + __builtin_amdgcn_exp2f(bv.w + qk[qi])), acc[qi][3]);
        }
    }
    #pragma unroll
    for (int qi = 0; qi < 4; ++qi)
        *(f32x4*)(Xp + (size_t)ks * 131072 + (size_t)(b * 64 + q0 + qi) * 512 + t * 4) = acc[qi];
}

// masked softmax over l (512) per (b,q) row; sums the 16 k-split partials
__global__ __launch_bounds__(512) void softmax_mask(
    const float* __restrict__ Xp, const int* __restrict__ mask,
    float* __restrict__ out)
{
    const int bq  = blockIdx.x;
    const int b   = bq >> 6;
    const int l   = threadIdx.x;
    const int wid = l >> 6;
    __shared__ float red[8];

    const size_t idx = (size_t)bq * 512 + l;
    float v = 0.f;
    #pragma unroll
    for (int p = 0; p < 16; ++p) v += Xp[idx + (size_t)p * 131072];
    v *= -2.f;
    const bool mk = (mask[b * 512 + l] != 0);
    v = mk ? v : -1e25f;

    float m = v;
    #pragma unroll
    for (int o = 32; o; o >>= 1) m = fmaxf(m, __shfl_xor(m, o));
    if ((l & 63) == 0) red[wid] = m;
    __syncthreads();
    #pragma unroll
    for (int i = 0; i < 8; ++i) m = fmaxf(m, red[i]);

    float e = __builtin_amdgcn_exp2f((v - m) * LOG2E);
    float s = e;
    #pragma unroll
    for (int o = 32; o; o >>= 1) s += __shfl_xor(s, o);
    __syncthreads();
    if ((l & 63) == 0) red[wid] = s;
    __syncthreads();
    s = 0.f;
    #pragma unroll
    for (int i = 0; i < 8; ++i) s += red[i];

    out[idx] = e / s;
}

extern "C" void kernel_launch(void* const* d_in, const int* in_sizes, int n_in,
                              void* d_out, int out_size, void* d_ws, size_t ws_size,
                              hipStream_t stream)
{
    const float* bert  = (const float*)d_in[0];   // (4,512,768) f32
    const float* query = (const float*)d_in[1];   // (4,64,768)  f32
    const int*   mask  = (const int*)  d_in[2];   // (4,512)     int32 (bool)
    const float* W_w   = (const float*)d_in[3];   // (768,1536)  f32
    const float* W_b   = (const float*)d_in[4];   // (768,)      f32
    const float* v_w   = (const float*)d_in[5];   // (1,768)     f32
    const float* v_b   = (const float*)d_in[6];   // (1,) unused (softmax shift-invariant)
    (void)v_b;

    float* bpT = (float*)d_ws;                     // [768][2048] f32 (k-major)
    float* qp  = bpT + (size_t)768 * 2048;         // [256][768]  f32
    float* Xp  = qp  + (size_t)256 * 768;          // [16][256][512] f32 partials
    unsigned short* Ahf = (unsigned short*)(Xp + (size_t)16 * 256 * 512);
    unsigned short* Alf = Ahf + (size_t)2304 * 768;
    unsigned short* Whf = Alf + (size_t)2304 * 768;
    unsigned short* Wlf = Whf + (size_t)1536 * 768;
    float* out = (float*)d_out;                    // (4,64,512) f32

    cast_frag<<<1440, 256, 0, stream>>>(bert, query, W_w, Ahf, Alf, Whf, Wlf);
    gemm_lds<<<432, 256, 0, stream>>>(Ahf, Alf, Whf, Wlf, W_b, bpT, qp);
    attn_dense4<<<dim3(64, 16), 128, 0, stream>>>(bpT, qp, v_w, Xp);
    softmax_mask<<<dim3(256), 512, 0, stream>>>(Xp, mask, out);
}